// Round 1
// baseline (3719.375 us; speedup 1.0000x reference)
//
#include <hip/hip_runtime.h>
#include <math.h>

#define N_NODES 100000
#define N_EDGES 1250000
#define NGRAPH 256
#define IN_DIM 8
#define DIM 64
#define OUT_DIM 2
#define BN_EPS 1e-5f

// ---------------- degree / norm precompute ----------------

__global__ void k_ones(float* __restrict__ deg) {
    int i = blockIdx.x * 256 + threadIdx.x;
    if (i < N_NODES) deg[i] = 1.0f;  // self-loop weight
}

__global__ void k_degacc(const int* __restrict__ dst, const float* __restrict__ edge_attr,
                         float* __restrict__ deg) {
    int e = blockIdx.x * 256 + threadIdx.x;
    if (e < N_EDGES) atomicAdd(&deg[dst[e]], edge_attr[2 * e + 1]);
}

__global__ void k_dinv(float* __restrict__ deg) {
    int i = blockIdx.x * 256 + threadIdx.x;
    if (i < N_NODES) {
        float d = deg[i];
        deg[i] = (d > 0.0f) ? rsqrtf(d) : 0.0f;
    }
}

__global__ void k_norm(const int* __restrict__ src, const int* __restrict__ dst,
                       const float* __restrict__ edge_attr, const float* __restrict__ dinv,
                       float* __restrict__ norm, float* __restrict__ selfnorm) {
    int idx = blockIdx.x * 256 + threadIdx.x;
    if (idx < N_EDGES) {
        norm[idx] = dinv[src[idx]] * edge_attr[2 * idx + 1] * dinv[dst[idx]];
    } else if (idx < N_EDGES + N_NODES) {
        int i = idx - N_EDGES;
        float d = dinv[i];
        selfnorm[i] = d * d;
    }
}

// ---------------- dense matmul: out[N,64] = h[N,K] @ W[K,64] ----------------

template <int K>
__global__ void k_matmul(const float* __restrict__ h, const float* __restrict__ W,
                         float* __restrict__ out) {
    __shared__ float Wsh[K * 64];
    __shared__ float hsh[4 * K];
    int tid = threadIdx.x;
    for (int i = tid; i < K * 64; i += 256) Wsh[i] = W[i];
    int row0 = blockIdx.x * 4;
    for (int i = tid; i < 4 * K; i += 256) {
        int rr = i / K, kk = i - rr * K;
        hsh[i] = h[(row0 + rr) * K + kk];
    }
    __syncthreads();
    int r = tid >> 6, c = tid & 63;
    float acc = 0.0f;
#pragma unroll
    for (int k = 0; k < K; ++k) acc += hsh[r * K + k] * Wsh[k * 64 + c];
    out[(row0 + r) * 64 + c] = acc;
}

// ---------------- self-loop init: out[i,:] = t[i,:] * selfnorm[i] ----------------

__global__ void k_self(const float* __restrict__ t, const float* __restrict__ selfnorm,
                       float* __restrict__ out) {
    int idx = blockIdx.x * 256 + threadIdx.x;  // over N*16 float4 groups
    if (idx >= N_NODES * 16) return;
    int i = idx >> 4;
    float s = selfnorm[i];
    float4 v = ((const float4*)t)[idx];
    v.x *= s; v.y *= s; v.z *= s; v.w *= s;
    ((float4*)out)[idx] = v;
}

// ---------------- edge scatter: out[dst,:] += t[src,:] * norm[e] ----------------

__global__ void k_scatter(const float* __restrict__ t, const int* __restrict__ src,
                          const int* __restrict__ dst, const float* __restrict__ norm,
                          float* __restrict__ out) {
    int idx = blockIdx.x * 256 + threadIdx.x;  // over E*16 float4 groups
    if (idx >= N_EDGES * 16) return;
    int e = idx >> 4, c4 = idx & 15;
    int s = src[e], d = dst[e];
    float nv = norm[e];
    float4 v = ((const float4*)(t + s * 64))[c4];
    float* o = out + d * 64 + c4 * 4;
    atomicAdd(o + 0, v.x * nv);
    atomicAdd(o + 1, v.y * nv);
    atomicAdd(o + 2, v.z * nv);
    atomicAdd(o + 3, v.w * nv);
}

// ---------------- bias + relu + BN stats ----------------

__global__ void k_postproc(float* __restrict__ h, const float* __restrict__ b,
                           float* __restrict__ stats) {
    __shared__ float s1[256], s2[256];
    int tid = threadIdx.x;
    int c = tid & 63;
    float bias = b[c];
    float sum = 0.0f, sumsq = 0.0f;
    for (int row = blockIdx.x * 4 + (tid >> 6); row < N_NODES; row += gridDim.x * 4) {
        float v = h[row * 64 + c] + bias;
        v = fmaxf(v, 0.0f);
        h[row * 64 + c] = v;
        sum += v;
        sumsq += v * v;
    }
    s1[tid] = sum; s2[tid] = sumsq;
    __syncthreads();
    if (tid < 64) {
        sum = s1[tid] + s1[tid + 64] + s1[tid + 128] + s1[tid + 192];
        sumsq = s2[tid] + s2[tid + 64] + s2[tid + 128] + s2[tid + 192];
        atomicAdd(&stats[c], sum);
        atomicAdd(&stats[64 + c], sumsq);
    }
}

// ---------------- per-channel scale/shift from stats ----------------

__global__ void k_bnprep(float* __restrict__ stats, const float* __restrict__ gamma,
                         const float* __restrict__ beta) {
    int c = threadIdx.x;
    const float invn = 1.0f / (float)N_NODES;
    float mu = stats[c] * invn;
    float var = stats[64 + c] * invn - mu * mu;
    float rs = rsqrtf(var + BN_EPS);
    float sc = gamma[c] * rs;
    stats[c] = sc;
    stats[64 + c] = beta[c] - sc * mu;
}

__global__ void k_bnapply(float* __restrict__ h, const float* __restrict__ stats) {
    int idx = blockIdx.x * 256 + threadIdx.x;  // over N*16 float4 groups
    if (idx >= N_NODES * 16) return;
    int c4 = idx & 15;
    float4 sc = ((const float4*)stats)[c4];
    float4 sh = ((const float4*)(stats + 64))[c4];
    float4 v = ((float4*)h)[idx];
    v.x = v.x * sc.x + sh.x;
    v.y = v.y * sc.y + sh.y;
    v.z = v.z * sc.z + sh.z;
    v.w = v.w * sc.w + sh.w;
    ((float4*)h)[idx] = v;
}

// ---------------- graph pooling ----------------

__global__ void k_pool(const int* __restrict__ batch, const float* __restrict__ h,
                       float* __restrict__ pooled) {
    int idx = blockIdx.x * 256 + threadIdx.x;  // over N*16 float4 groups
    if (idx >= N_NODES * 16) return;
    int i = idx >> 4, c4 = idx & 15;
    int g = batch[i];
    float4 v = ((const float4*)h)[idx];
    float* o = pooled + g * 64 + c4 * 4;
    atomicAdd(o + 0, v.x);
    atomicAdd(o + 1, v.y);
    atomicAdd(o + 2, v.z);
    atomicAdd(o + 3, v.w);
}

// ---------------- head: relu(pooled@W1+b1)@W2+b2, log_softmax ----------------

__global__ void k_head(const float* __restrict__ pooled, const float* __restrict__ w1,
                       const float* __restrict__ b1, const float* __restrict__ w2,
                       const float* __restrict__ b2, float* __restrict__ out) {
    __shared__ float p[64];
    __shared__ float hid[64];
    __shared__ float o[2];
    int g = blockIdx.x, c = threadIdx.x;
    p[c] = pooled[g * 64 + c];
    __syncthreads();
    float acc = b1[c];
#pragma unroll
    for (int k = 0; k < 64; ++k) acc += p[k] * w1[k * 64 + c];
    hid[c] = fmaxf(acc, 0.0f);
    __syncthreads();
    if (c < 2) {
        float a = b2[c];
#pragma unroll
        for (int k = 0; k < 64; ++k) a += hid[k] * w2[k * 2 + c];
        o[c] = a;
    }
    __syncthreads();
    if (c == 0) {
        float m = fmaxf(o[0], o[1]);
        float l = m + logf(expf(o[0] - m) + expf(o[1] - m));
        out[g * 2 + 0] = o[0] - l;
        out[g * 2 + 1] = o[1] - l;
    }
}

extern "C" void kernel_launch(void* const* d_in, const int* in_sizes, int n_in,
                              void* d_out, int out_size, void* d_ws, size_t ws_size,
                              hipStream_t stream) {
    const float* x        = (const float*)d_in[0];
    const int*   ei       = (const int*)d_in[1];
    const int*   batch    = (const int*)d_in[2];
    const float* edge_attr= (const float*)d_in[3];
    const float* W0       = (const float*)d_in[4];
    const float* b0       = (const float*)d_in[5];
    const float* Ws       = (const float*)d_in[6];
    const float* bs       = (const float*)d_in[7];
    const float* gammas   = (const float*)d_in[8];
    const float* betas    = (const float*)d_in[9];
    const float* lin1_w   = (const float*)d_in[10];
    const float* lin1_b   = (const float*)d_in[11];
    const float* lin2_w   = (const float*)d_in[12];
    const float* lin2_b   = (const float*)d_in[13];
    float* out = (float*)d_out;

    const int* src = ei;
    const int* dst = ei + N_EDGES;

    float* ws = (float*)d_ws;
    float* dinv     = ws;                       // N
    float* selfnorm = dinv + N_NODES;           // N
    float* norm     = selfnorm + N_NODES;       // E
    float* hA       = norm + N_EDGES;           // N*64
    float* hB       = hA + N_NODES * 64;        // N*64
    float* stats    = hB + N_NODES * 64;        // 128
    float* pooled   = stats + 128;              // G*64

    const int nblk_n   = (N_NODES + 255) / 256;
    const int nblk_e   = (N_EDGES + 255) / 256;
    const int nblk_en  = (N_EDGES + N_NODES + 255) / 256;
    const int nblk_n16 = (N_NODES * 16 + 255) / 256;
    const int nblk_e16 = (N_EDGES * 16 + 255) / 256;
    const int nblk_mm  = N_NODES / 4;  // 25000, N divisible by 4

    // degree + norm precompute (deg computed in-place in dinv buffer)
    k_ones<<<nblk_n, 256, 0, stream>>>(dinv);
    k_degacc<<<nblk_e, 256, 0, stream>>>(dst, edge_attr, dinv);
    k_dinv<<<nblk_n, 256, 0, stream>>>(dinv);
    k_norm<<<nblk_en, 256, 0, stream>>>(src, dst, edge_attr, dinv, norm, selfnorm);

    // ---- layer 0 (K=8) ----
    k_matmul<IN_DIM><<<nblk_mm, 256, 0, stream>>>(x, W0, hB);
    k_self<<<nblk_n16, 256, 0, stream>>>(hB, selfnorm, hA);
    k_scatter<<<nblk_e16, 256, 0, stream>>>(hB, src, dst, norm, hA);
    hipMemsetAsync(stats, 0, 128 * sizeof(float), stream);
    k_postproc<<<1024, 256, 0, stream>>>(hA, b0, stats);
    k_bnprep<<<1, 64, 0, stream>>>(stats, gammas, betas);
    k_bnapply<<<nblk_n16, 256, 0, stream>>>(hA, stats);

    // ---- layers 1..2 (K=64) ----
    for (int l = 0; l < 2; ++l) {
        k_matmul<DIM><<<nblk_mm, 256, 0, stream>>>(hA, Ws + l * 64 * 64, hB);
        k_self<<<nblk_n16, 256, 0, stream>>>(hB, selfnorm, hA);
        k_scatter<<<nblk_e16, 256, 0, stream>>>(hB, src, dst, norm, hA);
        hipMemsetAsync(stats, 0, 128 * sizeof(float), stream);
        k_postproc<<<1024, 256, 0, stream>>>(hA, bs + l * 64, stats);
        k_bnprep<<<1, 64, 0, stream>>>(stats, gammas + (l + 1) * 64, betas + (l + 1) * 64);
        k_bnapply<<<nblk_n16, 256, 0, stream>>>(hA, stats);
    }

    // ---- pool + head ----
    hipMemsetAsync(pooled, 0, NGRAPH * 64 * sizeof(float), stream);
    k_pool<<<nblk_n16, 256, 0, stream>>>(batch, hA, pooled);
    k_head<<<NGRAPH, 64, 0, stream>>>(pooled, lin1_w, lin1_b, lin2_w, lin2_b, out);
}

// Round 2
// 930.796 us; speedup vs baseline: 3.9959x; 3.9959x over previous
//
#include <hip/hip_runtime.h>
#include <math.h>

#define N_NODES 100000
#define N_EDGES 1250000
#define NGRAPH 256
#define IN_DIM 8
#define DIM 64
#define BN_EPS 1e-5f

#define NBLK_SCAN 391  // ceil(100000/256)

// ---------------- degree / norm precompute ----------------

__global__ void k_ones(float* __restrict__ deg) {
    int i = blockIdx.x * 256 + threadIdx.x;
    if (i < N_NODES) deg[i] = 1.0f;  // self-loop weight
}

__global__ void k_degacc(const int* __restrict__ dst, const float* __restrict__ edge_attr,
                         float* __restrict__ deg) {
    int e = blockIdx.x * 256 + threadIdx.x;
    if (e < N_EDGES) atomicAdd(&deg[dst[e]], edge_attr[2 * e + 1]);
}

__global__ void k_dinv(float* __restrict__ deg, float* __restrict__ selfnorm) {
    int i = blockIdx.x * 256 + threadIdx.x;
    if (i < N_NODES) {
        float d = deg[i];
        float r = (d > 0.0f) ? rsqrtf(d) : 0.0f;
        deg[i] = r;
        selfnorm[i] = r * r;
    }
}

// ---------------- CSR build (counting sort by dst) ----------------

__global__ void k_hist(const int* __restrict__ dst, int* __restrict__ counts) {
    int e = blockIdx.x * 256 + threadIdx.x;
    if (e < N_EDGES) atomicAdd(&counts[dst[e]], 1);
}

__global__ void k_blockreduce(const int* __restrict__ counts, int* __restrict__ blocksums) {
    __shared__ int sh[256];
    int t = threadIdx.x;
    int i = blockIdx.x * 256 + t;
    sh[t] = (i < N_NODES) ? counts[i] : 0;
    __syncthreads();
    for (int off = 128; off > 0; off >>= 1) {
        if (t < off) sh[t] += sh[t + off];
        __syncthreads();
    }
    if (t == 0) blocksums[blockIdx.x] = sh[0];
}

__global__ void k_scanblocksums(int* __restrict__ blocksums) {
    __shared__ int sh[512];
    int t = threadIdx.x;
    int v = (t < NBLK_SCAN) ? blocksums[t] : 0;
    sh[t] = v;
    __syncthreads();
    for (int off = 1; off < 512; off <<= 1) {
        int add = (t >= off) ? sh[t - off] : 0;
        __syncthreads();
        sh[t] += add;
        __syncthreads();
    }
    if (t < NBLK_SCAN) blocksums[t] = sh[t] - v;  // exclusive
}

__global__ void k_blockscan(const int* __restrict__ counts, const int* __restrict__ blocksums,
                            int* __restrict__ offsets, int* __restrict__ cursor) {
    __shared__ int sh[256];
    int t = threadIdx.x;
    int i = blockIdx.x * 256 + t;
    int v = (i < N_NODES) ? counts[i] : 0;
    sh[t] = v;
    __syncthreads();
    for (int off = 1; off < 256; off <<= 1) {
        int add = (t >= off) ? sh[t - off] : 0;
        __syncthreads();
        sh[t] += add;
        __syncthreads();
    }
    int excl = sh[t] - v + blocksums[blockIdx.x];
    if (i < N_NODES) { offsets[i] = excl; cursor[i] = excl; }
    if (i == N_NODES - 1) offsets[N_NODES] = excl + v;  // == E
}

__global__ void k_fill(const int* __restrict__ src, const int* __restrict__ dst,
                       const float* __restrict__ edge_attr, const float* __restrict__ dinv,
                       int* __restrict__ cursor, int2* __restrict__ csr) {
    int e = blockIdx.x * 256 + threadIdx.x;
    if (e >= N_EDGES) return;
    int s = src[e], d = dst[e];
    float w = edge_attr[2 * e + 1];
    int pos = atomicAdd(&cursor[d], 1);
    float nv = dinv[s] * w * dinv[d];
    csr[pos] = make_int2(s, __float_as_int(nv));
}

// ---------------- dense matmul: out[N,64] = affine(h)[N,K] @ W[K,64] ----------------

template <int K, bool AFFINE>
__global__ void k_matmul(const float* __restrict__ h, const float* __restrict__ W,
                         const float* __restrict__ stats, float* __restrict__ out) {
    __shared__ float Wsh[K * 64];
    __shared__ float hsh[4 * K];
    int tid = threadIdx.x;
    for (int i = tid; i < K * 64; i += 256) Wsh[i] = W[i];
    int row0 = blockIdx.x * 4;
    for (int i = tid; i < 4 * K; i += 256) {
        int rr = i / K, kk = i - rr * K;
        float v = h[(row0 + rr) * K + kk];
        if (AFFINE) v = v * stats[kk] + stats[64 + kk];
        hsh[i] = v;
    }
    __syncthreads();
    int r = tid >> 6, c = tid & 63;
    float acc = 0.0f;
#pragma unroll
    for (int k = 0; k < K; ++k) acc += hsh[r * K + k] * Wsh[k * 64 + c];
    out[(row0 + r) * 64 + c] = acc;
}

// ---------------- CSR gather: h[i,:] = relu(selfnorm[i]*t[i,:] + sum_e nv*t[src,:] + b) ----------------

__global__ void k_gather(const float* __restrict__ t, const int* __restrict__ offsets,
                         const int2* __restrict__ csr, const float* __restrict__ selfnorm,
                         const float* __restrict__ bias, float* __restrict__ out) {
    int wid = (blockIdx.x * 256 + threadIdx.x) >> 6;  // one wave per node
    int lane = threadIdx.x & 63;
    if (wid >= N_NODES) return;
    float acc = selfnorm[wid] * t[wid * 64 + lane];
    int e0 = offsets[wid], e1 = offsets[wid + 1];
    for (int e = e0; e < e1; ++e) {
        int2 p = csr[e];
        int s = p.x;
        float nv = __int_as_float(p.y);
        acc += nv * t[s * 64 + lane];
    }
    acc = fmaxf(acc + bias[lane], 0.0f);
    out[wid * 64 + lane] = acc;
}

// ---------------- BN stats (sum, sumsq per channel) ----------------

__global__ void k_bnstats(const float* __restrict__ h, float* __restrict__ stats) {
    __shared__ float s1[256], s2[256];
    int tid = threadIdx.x;
    int c = tid & 63;
    float sum = 0.0f, sumsq = 0.0f;
    for (int row = blockIdx.x * 4 + (tid >> 6); row < N_NODES; row += gridDim.x * 4) {
        float v = h[row * 64 + c];
        sum += v;
        sumsq += v * v;
    }
    s1[tid] = sum; s2[tid] = sumsq;
    __syncthreads();
    if (tid < 64) {
        sum = s1[tid] + s1[tid + 64] + s1[tid + 128] + s1[tid + 192];
        sumsq = s2[tid] + s2[tid + 64] + s2[tid + 128] + s2[tid + 192];
        atomicAdd(&stats[c], sum);
        atomicAdd(&stats[64 + c], sumsq);
    }
}

__global__ void k_bnprep(float* __restrict__ stats, const float* __restrict__ gamma,
                         const float* __restrict__ beta) {
    int c = threadIdx.x;
    const float invn = 1.0f / (float)N_NODES;
    float mu = stats[c] * invn;
    float var = stats[64 + c] * invn - mu * mu;
    float rs = rsqrtf(var + BN_EPS);
    float sc = gamma[c] * rs;
    stats[c] = sc;
    stats[64 + c] = beta[c] - sc * mu;
}

// ---------------- pooling over sorted batch (run-length local accumulation) ----------------

__global__ void k_pool(const int* __restrict__ batch, const float* __restrict__ h,
                       float* __restrict__ pooled, int* __restrict__ gcount) {
    const int ROWS = 512;
    int c = threadIdx.x & 63;
    int wsub = threadIdx.x >> 6;  // 0..3
    int start = blockIdx.x * ROWS;
    int end = start + ROWS; if (end > N_NODES) end = N_NODES;
    int cur = -1, cnt = 0;
    float acc = 0.0f;
    for (int r = start + wsub; r < end; r += 4) {
        int g = batch[r];
        float v = h[r * 64 + c];
        if (g != cur) {
            if (cur >= 0) {
                atomicAdd(&pooled[cur * 64 + c], acc);
                if (c == 0) atomicAdd(&gcount[cur], cnt);
            }
            cur = g; acc = 0.0f; cnt = 0;
        }
        acc += v; cnt += 1;
    }
    if (cur >= 0) {
        atomicAdd(&pooled[cur * 64 + c], acc);
        if (c == 0) atomicAdd(&gcount[cur], cnt);
    }
}

// ---------------- head: bn-affine fold, relu(p@W1+b1)@W2+b2, log_softmax ----------------

__global__ void k_head(const float* __restrict__ pooled, const int* __restrict__ gcount,
                       const float* __restrict__ stats, const float* __restrict__ w1,
                       const float* __restrict__ b1, const float* __restrict__ w2,
                       const float* __restrict__ b2, float* __restrict__ out) {
    __shared__ float p[64];
    __shared__ float hid[64];
    __shared__ float o[2];
    int g = blockIdx.x, c = threadIdx.x;
    // fold final BN affine: pooled_bn = sc*sum_v + count*sh
    p[c] = stats[c] * pooled[g * 64 + c] + (float)gcount[g] * stats[64 + c];
    __syncthreads();
    float acc = b1[c];
#pragma unroll
    for (int k = 0; k < 64; ++k) acc += p[k] * w1[k * 64 + c];
    hid[c] = fmaxf(acc, 0.0f);
    __syncthreads();
    if (c < 2) {
        float a = b2[c];
#pragma unroll
        for (int k = 0; k < 64; ++k) a += hid[k] * w2[k * 2 + c];
        o[c] = a;
    }
    __syncthreads();
    if (c == 0) {
        float m = fmaxf(o[0], o[1]);
        float l = m + logf(expf(o[0] - m) + expf(o[1] - m));
        out[g * 2 + 0] = o[0] - l;
        out[g * 2 + 1] = o[1] - l;
    }
}

extern "C" void kernel_launch(void* const* d_in, const int* in_sizes, int n_in,
                              void* d_out, int out_size, void* d_ws, size_t ws_size,
                              hipStream_t stream) {
    const float* x        = (const float*)d_in[0];
    const int*   ei       = (const int*)d_in[1];
    const int*   batch    = (const int*)d_in[2];
    const float* edge_attr= (const float*)d_in[3];
    const float* W0       = (const float*)d_in[4];
    const float* b0       = (const float*)d_in[5];
    const float* Ws       = (const float*)d_in[6];
    const float* bs       = (const float*)d_in[7];
    const float* gammas   = (const float*)d_in[8];
    const float* betas    = (const float*)d_in[9];
    const float* lin1_w   = (const float*)d_in[10];
    const float* lin1_b   = (const float*)d_in[11];
    const float* lin2_w   = (const float*)d_in[12];
    const float* lin2_b   = (const float*)d_in[13];
    float* out = (float*)d_out;

    const int* src = ei;
    const int* dst = ei + N_EDGES;

    // workspace layout (4B units)
    float* ws = (float*)d_ws;
    float* selfnorm = ws;                                  // 100000
    int*   offsets  = (int*)(ws + 100000);                 // 100002 (padded even)
    int2*  csr      = (int2*)(ws + 200002);                // 2*1250000
    float* hA       = ws + 2700002;                        // 6400000
    float* hB       = hA + (size_t)N_NODES * 64;           // 6400000
    float* stats    = hB + (size_t)N_NODES * 64;           // 128
    float* pooled   = stats + 128;                         // 16384
    int*   gcount   = (int*)(pooled + NGRAPH * 64);        // 256
    // transient aliases inside hA (all dead before first write of hA)
    float* dinv      = hA;                                 // 100000
    int*   counts    = (int*)(hA + 100000);                // 100000
    int*   cursor    = (int*)(hA + 200000);                // 100000
    int*   blocksums = (int*)(hA + 300000);                // 512

    const int nblk_n   = (N_NODES + 255) / 256;   // 391
    const int nblk_e   = (N_EDGES + 255) / 256;
    const int nblk_n16 = (N_NODES * 64 + 255) / 256;  // gather: wave per node
    const int nblk_mm  = N_NODES / 4;
    const int nblk_pool = (N_NODES + 511) / 512;

    // ---- degree / dinv / selfnorm ----
    k_ones<<<nblk_n, 256, 0, stream>>>(dinv);
    k_degacc<<<nblk_e, 256, 0, stream>>>(dst, edge_attr, dinv);
    k_dinv<<<nblk_n, 256, 0, stream>>>(dinv, selfnorm);

    // ---- CSR build ----
    hipMemsetAsync(counts, 0, N_NODES * sizeof(int), stream);
    k_hist<<<nblk_e, 256, 0, stream>>>(dst, counts);
    k_blockreduce<<<NBLK_SCAN, 256, 0, stream>>>(counts, blocksums);
    k_scanblocksums<<<1, 512, 0, stream>>>(blocksums);
    k_blockscan<<<NBLK_SCAN, 256, 0, stream>>>(counts, blocksums, offsets, cursor);
    k_fill<<<nblk_e, 256, 0, stream>>>(src, dst, edge_attr, dinv, cursor, csr);

    // ---- layer 0 (K=8, no input affine) ----
    k_matmul<IN_DIM, false><<<nblk_mm, 256, 0, stream>>>(x, W0, nullptr, hB);
    k_gather<<<nblk_n16, 256, 0, stream>>>(hB, offsets, csr, selfnorm, b0, hA);
    hipMemsetAsync(stats, 0, 128 * sizeof(float), stream);
    k_bnstats<<<512, 256, 0, stream>>>(hA, stats);
    k_bnprep<<<1, 64, 0, stream>>>(stats, gammas, betas);

    // ---- layers 1..2 (K=64, BN affine fused into matmul load) ----
    for (int l = 0; l < 2; ++l) {
        k_matmul<DIM, true><<<nblk_mm, 256, 0, stream>>>(hA, Ws + l * 64 * 64, stats, hB);
        k_gather<<<nblk_n16, 256, 0, stream>>>(hB, offsets, csr, selfnorm, bs + l * 64, hA);
        hipMemsetAsync(stats, 0, 128 * sizeof(float), stream);
        k_bnstats<<<512, 256, 0, stream>>>(hA, stats);
        k_bnprep<<<1, 64, 0, stream>>>(stats, gammas + (l + 1) * 64, betas + (l + 1) * 64);
    }

    // ---- pool (BN affine folded into head via counts) + head ----
    hipMemsetAsync(pooled, 0, (NGRAPH * 64 + NGRAPH) * sizeof(float), stream);
    k_pool<<<nblk_pool, 256, 0, stream>>>(batch, hA, pooled, gcount);
    k_head<<<NGRAPH, 64, 0, stream>>>(pooled, gcount, stats, lin1_w, lin1_b, lin2_w, lin2_b, out);
}